// Round 1
// baseline (4253.116 us; speedup 1.0000x reference)
//
#include <hip/hip_runtime.h>
#include <float.h>
#include <math.h>

#define H      1024
#define G4     4096
#define SLEN   128
#define VOUT   32000
#define NSTEP  51
#define EOS_ID 2
#define NB     256
#define BT     1024
#define NWAVES 16
#define GROWS  16      // G4/NB  gate rows per block
#define HROWS  4       // H/NB   ht_new rows per block
#define LROWS  125     // VOUT/NB logits rows per block
#define TOKS_OFF 51

__device__ __forceinline__ float wredsum(float v){
  v += __shfl_xor(v, 32, 64);
  v += __shfl_xor(v, 16, 64);
  v += __shfl_xor(v,  8, 64);
  v += __shfl_xor(v,  4, 64);
  v += __shfl_xor(v,  2, 64);
  v += __shfl_xor(v,  1, 64);
  return v;
}
__device__ __forceinline__ float wredmax(float v){
  v = fmaxf(v, __shfl_xor(v, 32, 64));
  v = fmaxf(v, __shfl_xor(v, 16, 64));
  v = fmaxf(v, __shfl_xor(v,  8, 64));
  v = fmaxf(v, __shfl_xor(v,  4, 64));
  v = fmaxf(v, __shfl_xor(v,  2, 64));
  v = fmaxf(v, __shfl_xor(v,  1, 64));
  return v;
}
// device-scope (cross-XCD coherent) load/store: bypass L2 so no fences needed
__device__ __forceinline__ float cload(const float* p){
  return __hip_atomic_load(p, __ATOMIC_RELAXED, __HIP_MEMORY_SCOPE_AGENT);
}
__device__ __forceinline__ int cloadi(const int* p){
  return __hip_atomic_load(p, __ATOMIC_RELAXED, __HIP_MEMORY_SCOPE_AGENT);
}
__device__ __forceinline__ void cstore(float* p, float v){
  __hip_atomic_store(p, v, __ATOMIC_RELAXED, __HIP_MEMORY_SCOPE_AGENT);
}
__device__ __forceinline__ void cstorei(int* p, int v){
  __hip_atomic_store(p, v, __ATOMIC_RELAXED, __HIP_MEMORY_SCOPE_AGENT);
}
__device__ __forceinline__ float sigm(float x){ return 1.0f/(1.0f+expf(-x)); }

// per-lane partial dot of a 1024-long row (16 elems/lane as 4x float4)
__device__ __forceinline__ float partdot(const float* __restrict__ a,
                                         const float* __restrict__ hp, int lane){
  const float4* a4 = (const float4*)a;
  const float4* h4 = (const float4*)hp;
  float s = 0.f;
#pragma unroll
  for(int k=0;k<4;k++){
    float4 x = a4[lane + 64*k];
    float4 y = h4[lane + 64*k];
    s = fmaf(x.x,y.x,s); s = fmaf(x.y,y.y,s);
    s = fmaf(x.z,y.z,s); s = fmaf(x.w,y.w,s);
  }
  return s;
}

extern "C" __global__ void __launch_bounds__(BT)
nmt_kernel(const int* __restrict__ src_ids,
           const float* __restrict__ embed_input,
           const float* __restrict__ W_ih_e, const float* __restrict__ W_hh_e,
           const float* __restrict__ b_ih_e, const float* __restrict__ b_hh_e,
           const float* __restrict__ W_li,  const float* __restrict__ b_li,
           const float* __restrict__ embed_target,
           const float* __restrict__ W_ih_d, const float* __restrict__ W_hh_d,
           const float* __restrict__ b_ih_d, const float* __restrict__ b_hh_d,
           const float* __restrict__ W_lt,  const float* __restrict__ b_lt,
           const float* __restrict__ W_tl,  const float* __restrict__ b_tl,
           float* __restrict__ out, float* __restrict__ ws,
           unsigned* __restrict__ counters)
{
  const int tid  = threadIdx.x;
  const int b    = blockIdx.x;
  const int w    = tid >> 6;
  const int lane = tid & 63;

  float* gatesA  = ws;                       // 4096
  float* gatesB  = ws + G4;                  // 4096
  float* scoresg = ws + 2*G4;                // 128
  float* htng    = ws + 2*G4 + SLEN;         // 1024
  float* pval    = ws + 2*G4 + SLEN + H;     // 256
  int*   pidx    = (int*)(ws + 2*G4 + SLEN + H + NB); // 256

  __shared__ __align__(16) float hbuf[2][H];
  __shared__ __align__(16) float c_lds[H];
  __shared__ __align__(16) float hsrow[H];
  __shared__ __align__(16) float htn_lds[H];
  __shared__ __align__(16) float xenc[SLEN][NWAVES];
  __shared__ __align__(16) float Mloc[HROWS][SLEN];
  __shared__ __align__(16) float sraw[SLEN];
  __shared__ __align__(16) float sc_e[SLEN];
  __shared__ float wred2[4];
  __shared__ float redv[NWAVES];
  __shared__ int   redi[NWAVES];
  __shared__ float gwhh_l[NWAVES];
  __shared__ float pv_l[NB];
  __shared__ int   pi_l[NB];
  __shared__ int   toks_lds[SLEN];
  __shared__ int   wid_sh, done_sh;

  int pc = 0;
#define GRID_BARRIER() do{                                                     \
    __syncthreads();                                                           \
    if(tid==0){                                                                \
      __hip_atomic_fetch_add(&counters[pc], 1u, __ATOMIC_RELEASE,              \
                             __HIP_MEMORY_SCOPE_AGENT);                        \
      while(__hip_atomic_load(&counters[pc], __ATOMIC_RELAXED,                 \
                              __HIP_MEMORY_SCOPE_AGENT) < (unsigned)NB){       \
        __builtin_amdgcn_s_sleep(1);                                           \
      }                                                                        \
    }                                                                          \
    pc++;                                                                      \
    __syncthreads();                                                           \
    asm volatile("" ::: "memory");                                             \
  }while(0)

  // ---- init ----
  hbuf[0][tid] = 0.f;
  c_lds[tid]   = 0.f;
  if (tid < SLEN) toks_lds[tid] = src_ids[tid];
  __syncthreads();

  // ---- Xenc precompute: xenc[t][w] = W_ih_e[row].x_t + b_ih_e + b_hh_e (block-local) ----
  {
    const int row = b*GROWS + w;
    const float4* wr = (const float4*)(W_ih_e + (size_t)row*H);
    float4 w0=wr[lane], w1=wr[lane+64], w2=wr[lane+128], w3=wr[lane+192];
    const float bias = b_ih_e[row] + b_hh_e[row];
    for(int t=0;t<SLEN;t++){
      const float4* xr = (const float4*)(embed_input + (size_t)toks_lds[t]*H);
      float4 x0=xr[lane], x1=xr[lane+64], x2=xr[lane+128], x3=xr[lane+192];
      float s;
      s = w0.x*x0.x;        s = fmaf(w0.y,x0.y,s); s = fmaf(w0.z,x0.z,s); s = fmaf(w0.w,x0.w,s);
      s = fmaf(w1.x,x1.x,s); s = fmaf(w1.y,x1.y,s); s = fmaf(w1.z,x1.z,s); s = fmaf(w1.w,x1.w,s);
      s = fmaf(w2.x,x2.x,s); s = fmaf(w2.y,x2.y,s); s = fmaf(w2.z,x2.z,s); s = fmaf(w2.w,x2.w,s);
      s = fmaf(w3.x,x3.x,s); s = fmaf(w3.y,x3.y,s); s = fmaf(w3.z,x3.z,s); s = fmaf(w3.w,x3.w,s);
      s = wredsum(s);
      if(lane==0) xenc[t][w] = s + bias;
    }
  }
  __syncthreads();

  // ---- encoder: 128 steps, 1 grid barrier each ----
  for(int t=0;t<SLEN;t++){
    float* gw = (t&1) ? gatesB : gatesA;
    {
      const int row = b*GROWS + w;
      float s = partdot(W_hh_e + (size_t)row*H, hbuf[0], lane);
      s = wredsum(s);
      if(lane==0) cstore(&gw[row], s + xenc[t][w]);
    }
    GRID_BARRIER();
    {
      const int d = tid;
      float gi = cload(&gw[d]);
      float gf = cload(&gw[d+H]);
      float gg = cload(&gw[d+2*H]);
      float go = cload(&gw[d+3*H]);
      float ii=sigm(gi), ff=sigm(gf), g2=tanhf(gg), oo=sigm(go);
      float c2 = fmaf(ff, c_lds[d], ii*g2);
      c_lds[d] = c2;
      float h2 = oo*tanhf(c2);
      hbuf[0][d] = h2;
      if (b==t) hsrow[d] = h2;   // block b<128 keeps hs_all[b] locally
    }
    __syncthreads();
    // M[r][t] = W_tl[r, :H] . hs_all[t]  (incremental, block-local)
    if (w < HROWS){
      const int r = b*HROWS + w;
      float s = partdot(W_tl + (size_t)r*2*H, hbuf[0], lane);
      s = wredsum(s);
      if(lane==0) Mloc[w][t] = s;
    }
    __syncthreads();
  }

  // ---- wid0 = argmax(W_li . hs + b_li) ----
  {
    float bestv=-FLT_MAX; int besti=0;
    for(int j=w; j<LROWS; j+=NWAVES){
      const int r = b*LROWS + j;
      float s = wredsum(partdot(W_li + (size_t)r*H, hbuf[0], lane));
      if(lane==0){
        float v = s + b_li[r];
        if(v>bestv){ bestv=v; besti=r; }
      }
    }
    if(lane==0){ redv[w]=bestv; redi[w]=besti; }
    __syncthreads();
    if(tid==0){
      float bv=redv[0]; int bi=redi[0];
      for(int i=1;i<NWAVES;i++)
        if(redv[i]>bv || (redv[i]==bv && redi[i]<bi)){ bv=redv[i]; bi=redi[i]; }
      cstore(&pval[b], bv); cstorei(&pidx[b], bi);
    }
  }
  GRID_BARRIER();
  {
    if(tid<NB){ pv_l[tid]=cload(&pval[tid]); pi_l[tid]=cloadi(&pidx[tid]); }
    __syncthreads();
    if(tid==0){
      float bv=pv_l[0]; int bi=pi_l[0];
      for(int i=1;i<NB;i++)
        if(pv_l[i]>bv || (pv_l[i]==bv && pi_l[i]<bi)){ bv=pv_l[i]; bi=pi_l[i]; }
      wid_sh = bi;
      done_sh = (bi==EOS_ID) ? 1 : 0;
    }
    __syncthreads();
  }

  // ---- first decoder cell: (ht0, cx) = cell(E[wid0], hs, cx_enc) ----
  {
    const int row = b*GROWS + w;
    const float* tk = embed_target + (size_t)wid_sh*H;
    float s = partdot(W_ih_d + (size_t)row*H, tk, lane)
            + partdot(W_hh_d + (size_t)row*H, hbuf[0], lane);
    s = wredsum(s);
    if(lane==0) cstore(&gatesA[row], s + b_ih_d[row] + b_hh_d[row]);
  }
  GRID_BARRIER();
  {
    const int d = tid;
    float gi=cload(&gatesA[d]), gf=cload(&gatesA[d+H]),
          gg=cload(&gatesA[d+2*H]), go=cload(&gatesA[d+3*H]);
    float ii=sigm(gi), ff=sigm(gf), g2=tanhf(gg), oo=sigm(go);
    float c2=fmaf(ff, c_lds[d], ii*g2);
    c_lds[d]=c2;
    hbuf[1][d]=oo*tanhf(c2);
  }
  __syncthreads();
  if(b<SLEN && w==0){
    float s = wredsum(partdot(hsrow, hbuf[1], lane));
    if(lane==0) cstore(&scoresg[b], s);
  }
  {
    const int row=b*GROWS+w;
    float s=wredsum(partdot(W_hh_d + (size_t)row*H, hbuf[1], lane));
    if(lane==0) gwhh_l[w]=s;
  }
  GRID_BARRIER();

  // ---- decode: 51 steps, 2 barriers each ----
  int cur = 1;
  for(int k=0;k<NSTEP;k++){
    float* hk = hbuf[cur];
    float* hn = hbuf[cur^1];
    // -------- P1 --------
    if(k>0){
      if(tid<NB){ pv_l[tid]=cload(&pval[tid]); pi_l[tid]=cloadi(&pidx[tid]); }
      __syncthreads();
      if(tid==0){
        float bv=pv_l[0]; int bi=pi_l[0];
        for(int i=1;i<NB;i++)
          if(pv_l[i]>bv || (pv_l[i]==bv && pi_l[i]<bi)){ bv=pv_l[i]; bi=pi_l[i]; }
        int iseos=(bi==EOS_ID)?1:0;
        int outtok=(done_sh|iseos)?-1:bi;
        if(b==0) out[k-1]=(float)outtok;
        done_sh |= iseos;
        wid_sh = bi;
      }
      __syncthreads();
    }
    // softmax over 128 scores (redundant per block)
    if(tid<SLEN) sraw[tid]=cload(&scoresg[tid]);
    __syncthreads();
    if(tid<SLEN){
      float m = wredmax(sraw[tid]);
      if(lane==0) wred2[w]=m;
    }
    __syncthreads();
    if(tid<SLEN){
      float mx=fmaxf(wred2[0],wred2[1]);
      float e=expf(sraw[tid]-mx);
      sc_e[tid]=e;
      float z=wredsum(e);
      if(lane==0) wred2[2+w]=z;
    }
    __syncthreads();
    // decoder LSTM gates for this step
    {
      const int row=b*GROWS+w;
      const float* tk=embed_target + (size_t)wid_sh*H;
      float s=wredsum(partdot(W_ih_d + (size_t)row*H, tk, lane));
      if(lane==0) cstore(&gatesA[row], s + gwhh_l[w] + b_ih_d[row] + b_hh_d[row]);
    }
    // ht_new rows via M-trick
    if(w<HROWS){
      const int r=b*HROWS+w;
      float invZ=1.f/(wred2[2]+wred2[3]);
      float att=fmaf(sc_e[2*lane],Mloc[w][2*lane], sc_e[2*lane+1]*Mloc[w][2*lane+1]);
      float s=partdot(W_tl + (size_t)r*2*H + H, hk, lane);
      float tot=wredsum(fmaf(att,invZ,s));
      if(lane==0) cstore(&htng[r], tanhf(tot + b_tl[r]));
    }
    GRID_BARRIER();
    // -------- P2 --------
    {
      htn_lds[tid]=cload(&htng[tid]);
      const int d=tid;
      float gi=cload(&gatesA[d]), gf=cload(&gatesA[d+H]),
            gg=cload(&gatesA[d+2*H]), go=cload(&gatesA[d+3*H]);
      float ii=sigm(gi), ff=sigm(gf), g2=tanhf(gg), oo=sigm(go);
      float c2=fmaf(ff,c_lds[d],ii*g2);
      c_lds[d]=c2;
      hn[d]=oo*tanhf(c2);
    }
    __syncthreads();
    {
      float bestv=-FLT_MAX; int besti=0;
      const size_t obase = TOKS_OFF + (size_t)k*VOUT;
      for(int j=w;j<LROWS;j+=NWAVES){
        const int r=b*LROWS+j;
        float s=wredsum(partdot(W_lt + (size_t)r*H, htn_lds, lane));
        if(lane==0){
          float v=s+b_lt[r];
          out[obase + r]=v;
          if(v>bestv){bestv=v;besti=r;}
        }
      }
      if(lane==0){ redv[w]=bestv; redi[w]=besti; }
    }
    if(b<SLEN && w==0){
      float s=wredsum(partdot(hsrow, hn, lane));
      if(lane==0) cstore(&scoresg[b], s);
    }
    {
      const int row=b*GROWS+w;
      float s=wredsum(partdot(W_hh_d + (size_t)row*H, hn, lane));
      if(lane==0) gwhh_l[w]=s;
    }
    __syncthreads();
    if(tid==0){
      float bv=redv[0]; int bi=redi[0];
      for(int i=1;i<NWAVES;i++)
        if(redv[i]>bv || (redv[i]==bv && redi[i]<bi)){ bv=redv[i]; bi=redi[i]; }
      cstore(&pval[b], bv); cstorei(&pidx[b], bi);
    }
    GRID_BARRIER();
    cur ^= 1;
  }

  // ---- epilogue: last token ----
  if(b==0){
    if(tid<NB){ pv_l[tid]=cload(&pval[tid]); pi_l[tid]=cloadi(&pidx[tid]); }
    __syncthreads();
    if(tid==0){
      float bv=pv_l[0]; int bi=pi_l[0];
      for(int i=1;i<NB;i++)
        if(pv_l[i]>bv || (pv_l[i]==bv && pi_l[i]<bi)){ bv=pv_l[i]; bi=pi_l[i]; }
      int iseos=(bi==EOS_ID)?1:0;
      out[NSTEP-1]=(float)((done_sh|iseos)?-1:bi);
    }
  }
#undef GRID_BARRIER
}

extern "C" void kernel_launch(void* const* d_in, const int* in_sizes, int n_in,
                              void* d_out, int out_size, void* d_ws, size_t ws_size,
                              hipStream_t stream) {
  const int*   src_ids      = (const int*)  d_in[0];
  const float* embed_input  = (const float*)d_in[1];
  const float* W_ih_e       = (const float*)d_in[2];
  const float* W_hh_e       = (const float*)d_in[3];
  const float* b_ih_e       = (const float*)d_in[4];
  const float* b_hh_e       = (const float*)d_in[5];
  const float* W_li         = (const float*)d_in[6];
  const float* b_li         = (const float*)d_in[7];
  const float* embed_target = (const float*)d_in[8];
  const float* W_ih_d       = (const float*)d_in[9];
  const float* W_hh_d       = (const float*)d_in[10];
  const float* b_ih_d       = (const float*)d_in[11];
  const float* b_hh_d       = (const float*)d_in[12];
  const float* W_lt         = (const float*)d_in[13];
  const float* b_lt         = (const float*)d_in[14];
  const float* W_tl         = (const float*)d_in[15];
  const float* b_tl         = (const float*)d_in[16];
  float*       out          = (float*)d_out;
  unsigned*    counters     = (unsigned*)d_ws;
  float*       wsf          = (float*)d_ws + 1024;   // data region after 4KB counter area

  // zero the barrier counters every launch (graph-capture-safe)
  hipMemsetAsync(d_ws, 0, 4096, stream);

  void* args[] = {
    (void*)&src_ids, (void*)&embed_input,
    (void*)&W_ih_e, (void*)&W_hh_e, (void*)&b_ih_e, (void*)&b_hh_e,
    (void*)&W_li, (void*)&b_li, (void*)&embed_target,
    (void*)&W_ih_d, (void*)&W_hh_d, (void*)&b_ih_d, (void*)&b_hh_d,
    (void*)&W_lt, (void*)&b_lt, (void*)&W_tl, (void*)&b_tl,
    (void*)&out, (void*)&wsf, (void*)&counters
  };

  hipError_t err = hipLaunchCooperativeKernel((const void*)nmt_kernel,
                                              dim3(NB), dim3(BT), args, 0, stream);
  if (err != hipSuccess) {
    // fallback: plain launch; 256 blocks x 1024 threads <= 1 block/CU, co-resident
    nmt_kernel<<<dim3(NB), dim3(BT), 0, stream>>>(
        src_ids, embed_input, W_ih_e, W_hh_e, b_ih_e, b_hh_e,
        W_li, b_li, embed_target, W_ih_d, W_hh_d, b_ih_d, b_hh_d,
        W_lt, b_lt, W_tl, b_tl, out, wsf, counters);
  }
}